// Round 15
// baseline (5888.177 us; speedup 1.0000x reference)
//
#include <hip/hip_runtime.h>
#include <hip/hip_bf16.h>

typedef __attribute__((ext_vector_type(8))) __bf16 bf16x8;
typedef __attribute__((ext_vector_type(4))) float f32x4;
typedef unsigned short u16;
typedef unsigned int u32;
typedef unsigned long long u64;

#define NB 64      // batch
#define NT 512     // timesteps
#define NH 1024    // hidden
#define NOB 256    // obs dim
#define NWG 256    // persistent workgroups (2 independent 128-WG domains)
#define HALF_WG 128
#define G4H 4096   // 4*NH
#define BH (NB*NH) // h-slot elements

// LDS segment layout (per-WG): X = [obs 32x256 | h0 32x1024 | h1 32x1024] bf16
#define S_OBS 0
#define S_H0  16384
#define S_H1  81920
#define LDS_TOTAL 147456

#define KT0 10   // k-tiles per wave, layer 0 (K=1280 / 4 kq / 32)
#define KT1 16   // k-tiles per wave, layer 1 (K=2048 / 4 kq / 32)

#define AS_RELAXED __ATOMIC_RELAXED
#define SCOPE_AGENT __HIP_MEMORY_SCOPE_AGENT
#define KEEPW(x) asm volatile("" : "+v"(x))

// raw sync primitives; sched_barrier(0) pins ordering (guide rule #18)
#define SBAR  do { asm volatile("s_barrier" ::: "memory"); __builtin_amdgcn_sched_barrier(0); } while (0)
#define LGKM0 do { asm volatile("s_waitcnt lgkmcnt(0)" ::: "memory"); __builtin_amdgcn_sched_barrier(0); } while (0)
#define VMW0  do { asm volatile("s_waitcnt vmcnt(0)" ::: "memory"); __builtin_amdgcn_sched_barrier(0); } while (0)
#define VMW8  do { asm volatile("s_waitcnt vmcnt(8)" ::: "memory"); __builtin_amdgcn_sched_barrier(0); } while (0)

__device__ __forceinline__ u16 f2bf(float f) {
  __hip_bfloat16 h = __float2bfloat16(f);
  return *reinterpret_cast<u16*>(&h);
}
__device__ __forceinline__ float sigm(float x) { return 1.f / (1.f + __expf(-x)); }
__device__ __forceinline__ float tanh_f(float x) {
  float e = __expf(2.f * x);
  return 1.f - 2.f / (e + 1.f);
}

// async global->LDS DMA, 16B/lane. LDS dest = wave-uniform base + lane*16;
// global src is per-lane (carries the XOR swizzle). Tracked by vmcnt.
__device__ __forceinline__ void gload_lds16(const void* g, void* l) {
  __builtin_amdgcn_global_load_lds(
      (const __attribute__((address_space(1))) void*)g,
      (__attribute__((address_space(3))) void*)l, 16, 0, 0);
}

// LLC-coherent 16B load (single-slot h1 fallback path only).
__device__ __forceinline__ int4 load_b128_coh(const void* p) {
  int4 v;
  asm volatile("global_load_dwordx4 %0, %1, off sc0 sc1\n\ts_waitcnt vmcnt(0)"
               : "=v"(v) : "v"(p) : "memory");
  return v;
}
__device__ __forceinline__ u64 AL64(const u64* p) {
  return __hip_atomic_load(p, AS_RELAXED, SCOPE_AGENT);
}

// Full barrier (bar2): r7-proven flat-poll per 128-WG domain.
// Arrival after __syncthreads (vmcnt(0) drained -> sc1 data at LLC).
__device__ __forceinline__ void gridbar(int* barD, int myleaf, int gen) {
  __syncthreads();
  if (threadIdx.x < 64) {
    const int lane = threadIdx.x;
    if (lane == 0)
      __hip_atomic_fetch_add(&barD[myleaf * 32], 1, AS_RELAXED, SCOPE_AGENT);
    const int tgt = HALF_WG * gen;
    for (;;) {
      int v = (lane < 16)
            ? __hip_atomic_load(&barD[lane * 32], AS_RELAXED, SCOPE_AGENT) : 0;
#pragma unroll
      for (int off = 8; off; off >>= 1) v += __shfl_xor(v, off);
      v = __shfl(v, 0);
      if (v >= tgt) break;
      __builtin_amdgcn_s_sleep(1);
    }
  }
  __syncthreads();
}

// Per-wave k-tile -> absolute k in X-space (r3-proven mapping).
__device__ __host__ __forceinline__ int wavek0(int kq, int kt) {
  return kt < 2 ? kq * 64 + kt * 32 : 256 + kq * 256 + (kt - 2) * 32;
}
__device__ __host__ __forceinline__ int wavek1(int kq, int kt) {
  return kq * 512 + kt * 32;
}

// Pack fp32 [Wih|Whh] into bf16 MFMA B-fragments (r3-proven layout).
template<int LAYER>
__global__ void __launch_bounds__(256)
pack_weights(const float* __restrict__ Wih, const float* __restrict__ Whh,
             u16* __restrict__ wp) {
  constexpr int KT = LAYER ? KT1 : KT0;
  constexpr int KIN = LAYER ? 1024 : 256;
  const int total = 128 * 2 * 4 * KT * 64;
  for (int idx = blockIdx.x * blockDim.x + threadIdx.x; idx < total;
       idx += gridDim.x * blockDim.x) {
    int lane = idx & 63;
    int q = idx >> 6;
    int kt = q % KT; q /= KT;
    int kq = q & 3; q >>= 2;
    int nt = q & 1; q >>= 1;
    int slice = q;
    int outr = slice * 32 + nt * 16 + (lane & 15);
    int kb = (LAYER ? wavek1(kq, kt) : wavek0(kq, kt)) + (lane >> 4) * 8;
    union { u16 uu[8]; int4 qv; } vv;
#pragma unroll
    for (int j = 0; j < 8; ++j) {
      int k = kb + j;
      float f = (k < KIN) ? Wih[(long)outr * KIN + k] : Whh[(long)outr * NH + (k - KIN)];
      vv.uu[j] = f2bf(f);
    }
    reinterpret_cast<int4*>(wp)[idx] = vv.qv;
  }
}

// obsT[t][b][k] = bf16(obs[b][t][k])
__global__ void __launch_bounds__(256)
transpose_obs(const float* __restrict__ obs, u16* __restrict__ obsT) {
  long idx = (long)blockIdx.x * blockDim.x + threadIdx.x;
  if (idx >= (long)NT * NB * NOB) return;
  int k = (int)(idx & (NOB - 1));
  long r = idx >> 8;
  int b = (int)(r & (NB - 1));
  int t = (int)(r >> 6);
  obsT[idx] = f2bf(obs[((long)b * NT + t) * NOB + k]);
}

// Fused two-layer persistent kernel (r14 structure + r15 sector-polled bar1).
// Leaf = slice>>3 (8 contiguous slices = 256 contiguous z columns): leaf L's
// counter reaching 8*gen means z columns [256L, 256L+256) are at LLC.
// bar1 becomes ARRIVAL-ONLY; P2 wave k polls just leaves {4g+k} per gate g
// (out g*1024+e -> leaf (g*1024+e)>>8; e in [128w,128w+128) -> k = w>>1),
// interleaving each wait with that gate's z loads. GEMM-only WGs skip any
// bar1 wait. z WAR is fenced by bar2 (P2 consumes before bar2 arrival).
template<bool H1COH>
__global__ void __launch_bounds__(512)
fused_lstm(const u16* __restrict__ obsT,
           const u16* __restrict__ wp0, const u16* __restrict__ wp1,
           const float* __restrict__ b0, const float* __restrict__ gn0,
           const float* __restrict__ cn0,
           const float* __restrict__ b1, const float* __restrict__ gn1,
           const float* __restrict__ cn1,
           u16* __restrict__ h0hist, u16* __restrict__ h1buf, long long h1step,
           float* __restrict__ zbuf, float* __restrict__ feat,
           int* __restrict__ bar) {
  extern __shared__ char smem[];
  f32x4* sred = reinterpret_cast<f32x4*>(smem + S_H1);   // aliases h1-seg (dead)
  float* p2red = reinterpret_cast<float*>(smem + S_H0);  // aliases h0-seg (dead)

  const int tid = threadIdx.x;
  const int lane = tid & 63;
  const int wave = tid >> 6;
  const int nt = wave & 1;
  const int kq = wave >> 1;
  const int col = lane & 15;
  const int rgrp = lane >> 4;
  const int wg = blockIdx.x;
  const int bg = wg >> 7;
  const int slice = wg & 127;
  const int kl = (wave & 1) * 64 + lane;  // h-seg chunk-in-row for DMA
  const int w2 = wave >> 1;               // h-seg row group for DMA
  int* barD = bar + bg * 512;             // own domain's 16-leaf region
  const int myleaf = slice >> 3;          // r15: sector-contiguous leaf

  // ---- persistent weight fragments (both layers) ----
  bf16x8 wf0[KT0], wf1[KT1];
  {
    const bf16x8* p0 = reinterpret_cast<const bf16x8*>(wp0)
                     + ((size_t)((slice * 2 + nt) * 4 + kq) * KT0) * 64 + lane;
#pragma unroll
    for (int u = 0; u < KT0; ++u) { wf0[u] = p0[u * 64]; KEEPW(wf0[u]); }
    const bf16x8* p1 = reinterpret_cast<const bf16x8*>(wp1)
                     + ((size_t)((slice * 2 + nt) * 4 + kq) * KT1) * 64 + lane;
#pragma unroll
    for (int u = 0; u < KT1; ++u) { wf1[u] = p1[u * 64]; KEEPW(wf1[u]); }
  }

  // ---- phase-2 constants/state (slice<64 in each domain, domain-local) ----
  const bool p2wg = (slice < 64);
  const int l2 = (slice >> 5) & 1;            // 0: layer0, 1: layer1
  const int prow = bg * 32 + (slice & 31);    // own-domain batch row
  const int ej = tid * 2;
  float gn[8];
  float cw0 = 0.f, cw1 = 0.f;
  float c0 = 0.f, c1 = 0.f;
  if (p2wg) {
    const float* gnp = l2 ? gn1 : gn0;
    const float* cnp = l2 ? cn1 : cn0;
#pragma unroll
    for (int g = 0; g < 4; ++g) {
      gn[g * 2]     = gnp[g * NH + ej];
      gn[g * 2 + 1] = gnp[g * NH + ej + 1];
    }
    cw0 = cnp[ej];
    cw1 = cnp[ej + 1];
  }
  constexpr float inv = 1.f / 1024.f;

  // ---- prologue: issue obs(0) DMA (drained by round 0's VMW8, in-order) ----
  {
    const u16* os = obsT + (size_t)(bg * 32) * NOB;
#pragma unroll
    for (int i = 0; i < 2; ++i) {
      const int row = 16 * i + 2 * wave + (lane >> 5);
      gload_lds16(os + (size_t)row * NOB + (size_t)(((lane & 31) ^ (row & 7)) * 8),
                  smem + S_OBS + (i * 512 + wave * 64) * 16);
    }
  }

  int gen = 0;

  for (int r = 0; r <= NT; ++r) {
    // -------- issue h0 / h1 staging DMA (slot r) --------
    const u16* h0s = h0hist + (size_t)r * BH + (size_t)(bg * 32) * NH;
    const u16* h1s = h1buf + (size_t)r * h1step + (size_t)(bg * 32) * NH;
#pragma unroll
    for (int i = 0; i < 8; ++i) {
      const int row = i * 4 + w2;
      const int koff = (kl ^ (row & 7)) * 8;
      gload_lds16(h0s + (size_t)row * NH + koff,
                  smem + S_H0 + (i * 512 + wave * 64) * 16);
    }
    if constexpr (!H1COH) {
#pragma unroll
      for (int i = 0; i < 8; ++i) {
        const int row = i * 4 + w2;
        const int koff = (kl ^ (row & 7)) * 8;
        gload_lds16(h1s + (size_t)row * NH + koff,
                    smem + S_H1 + (i * 512 + wave * 64) * 16);
      }
      VMW8;   // obs leftovers + own h0 landed (h1's 8 still in flight)
      SBAR;   // all waves' h0 in LDS; h1 DMA flies across the barrier
    } else {
      // fallback: manual coherent h1 staging (single-slot buffer)
#pragma unroll 1
      for (int c = tid; c < 4096; c += 512) {
        int row = c >> 7, kc = c & 127;
        int4 v = load_b128_coh(h1s + (size_t)row * NH + kc * 8);
        *reinterpret_cast<int4*>(smem + S_H1 + row * 2048 + ((kc ^ (row & 7)) << 4)) = v;
      }
      VMW0; LGKM0;
      SBAR;   // obs + h0 + h1 all in LDS
    }

    // -------- L0 GEMM (reads S_OBS + S_H0 only) --------
    f32x4 a00 = {0,0,0,0}, a01 = {0,0,0,0};
    f32x4 a10 = {0,0,0,0}, a11 = {0,0,0,0};
    if (r < NT) {
#pragma unroll
      for (int kt = 0; kt < KT0; ++kt) {
        const int base   = (kt < 2) ? S_OBS : S_H0;
        const int rowstr = (kt < 2) ? 512 : 2048;
        const int chunk0 = (kt < 2) ? (kq * 8 + kt * 4) : (kq * 32 + (kt - 2) * 4);
        const int sw = (((chunk0 + rgrp) ^ (col & 7)) << 4);
        bf16x8 am0 = *reinterpret_cast<const bf16x8*>(smem + base + col * rowstr + sw);
        bf16x8 am1 = *reinterpret_cast<const bf16x8*>(smem + base + (16 + col) * rowstr + sw);
        a00 = __builtin_amdgcn_mfma_f32_16x16x32_bf16(am0, wf0[kt], a00, 0, 0, 0);
        a01 = __builtin_amdgcn_mfma_f32_16x16x32_bf16(am1, wf0[kt], a01, 0, 0, 0);
      }
    }
    if constexpr (!H1COH) {
      VMW0;   // own h1 DMA landed
      SBAR;   // everyone's h1 landed
    }

    // -------- L1 GEMM (reads S_H0 + S_H1) --------
    if (r >= 1) {
      const int base = (kq < 2) ? S_H0 : S_H1;
#pragma unroll
      for (int kt = 0; kt < KT1; ++kt) {
        const int chunk0 = (kq & 1) * 64 + kt * 4;
        const int sw = (((chunk0 + rgrp) ^ (col & 7)) << 4);
        bf16x8 am0 = *reinterpret_cast<const bf16x8*>(smem + base + col * 2048 + sw);
        bf16x8 am1 = *reinterpret_cast<const bf16x8*>(smem + base + (16 + col) * 2048 + sw);
        a10 = __builtin_amdgcn_mfma_f32_16x16x32_bf16(am0, wf1[kt], a10, 0, 0, 0);
        a11 = __builtin_amdgcn_mfma_f32_16x16x32_bf16(am1, wf1[kt], a11, 0, 0, 0);
      }
    }
    LGKM0;
    SBAR;   // all LDS X reads done (obs/h0/h1 segments now dead)

    // -------- cross-wave K-reduction in LDS; z -> LLC (sc1) --------
    {
      f32x4* pw = sred + wave * 512 + lane;
      pw[0 * 64] = a00;  // l=0,m=0
      pw[1 * 64] = a01;  // l=0,m=1
      pw[2 * 64] = a10;  // l=1,m=0
      pw[3 * 64] = a11;  // l=1,m=1
    }
    LGKM0;
    SBAR;
    {
      const int q = tid >> 6, ln = tid & 63;
      const int fcol = ln & 15, frg = ln >> 4;
      const int lm = q & 3;      // l*2+m
      const int nq2 = q >> 2;    // out-half to reduce
      f32x4 s = sred[(nq2 + 0) * 512 + lm * 64 + ln]
              + sred[(nq2 + 2) * 512 + lm * 64 + ln]
              + sred[(nq2 + 4) * 512 + lm * 64 + ln]
              + sred[(nq2 + 6) * 512 + lm * 64 + ln];
      const int l = lm >> 1, m = lm & 1;
      const bool zv = l ? (r >= 1) : (r < NT);
      if (zv) {
        const int outg = slice * 32 + nq2 * 16 + fcol;
        const float bv = (l ? b1 : b0)[outg];
        float* zr = zbuf + ((size_t)l * NB + bg * 32 + m * 16 + frg * 4) * G4H + outg;
#pragma unroll
        for (int j = 0; j < 4; ++j)
          __hip_atomic_store(&zr[(size_t)j * G4H], s[j] + bv, AS_RELAXED, SCOPE_AGENT);
      }
    }

    // -------- bar1: ARRIVAL ONLY (z-ready signal per leaf/sector) --------
    const int bar1gen = ++gen;
    __syncthreads();   // drains z sc1 stores (vmcnt 0) before arrival
    if (tid == 0)
      __hip_atomic_fetch_add(&barD[myleaf * 32], 1, AS_RELAXED, SCOPE_AGENT);

    // -------- obs(r+1) prefetch DMA (drains during phase-2 / bar2) --------
    if (r + 1 < NT) {
      const u16* os = obsT + (size_t)(r + 1) * (NB * NOB) + (size_t)(bg * 32) * NOB;
#pragma unroll
      for (int i = 0; i < 2; ++i) {
        const int row = 16 * i + 2 * wave + (lane >> 5);
        gload_lds16(os + (size_t)row * NOB + (size_t)(((lane & 31) ^ (row & 7)) * 8),
                    smem + S_OBS + (i * 512 + wave * 64) * 16);
      }
    }

    // -------- phase 2: sector-polled z consumption --------
    if (p2wg && (l2 ? (r >= 1) : (r < NT))) {
      const u64* zq = reinterpret_cast<const u64*>(
          zbuf + ((size_t)l2 * NB + prow) * G4H);
      const int k2 = wave >> 1;   // element range [128*wave, +128) -> leaf 4g+k2
      union UZ { u64 q; float f[2]; } vz[4];
      float ss[4];
#pragma unroll
      for (int g = 0; g < 4; ++g) {
        if (lane == 0) {
          while (__hip_atomic_load(&barD[(4 * g + k2) * 32], AS_RELAXED, SCOPE_AGENT)
                 < 8 * bar1gen)
            __builtin_amdgcn_s_sleep(1);
        }
        __builtin_amdgcn_sched_barrier(0);
        vz[g].q = AL64(zq + g * 512 + tid);
        ss[g] = vz[g].f[0] * vz[g].f[0] + vz[g].f[1] * vz[g].f[1];
      }
#pragma unroll
      for (int off = 32; off; off >>= 1) {
        ss[0] += __shfl_xor(ss[0], off);
        ss[1] += __shfl_xor(ss[1], off);
        ss[2] += __shfl_xor(ss[2], off);
        ss[3] += __shfl_xor(ss[3], off);
      }
      if (lane == 0) {
        float* sp = p2red + wave * 4;
        sp[0] = ss[0]; sp[1] = ss[1]; sp[2] = ss[2]; sp[3] = ss[3];
      }
      __syncthreads();
      float t0 = 0.f, t1 = 0.f, t2 = 0.f, t3 = 0.f;
#pragma unroll
      for (int w = 0; w < 8; ++w) {
        t0 += p2red[w * 4 + 0]; t1 += p2red[w * 4 + 1];
        t2 += p2red[w * 4 + 2]; t3 += p2red[w * 4 + 3];
      }
      const float r0 = rsqrtf(t0 * inv + 1e-6f);
      const float r1 = rsqrtf(t1 * inv + 1e-6f);
      const float r2 = rsqrtf(t2 * inv + 1e-6f);
      const float r3 = rsqrtf(t3 * inv + 1e-6f);
      const float i0 = sigm(vz[0].f[0] * gn[0] * r0), i1 = sigm(vz[0].f[1] * gn[1] * r0);
      const float f0 = sigm(vz[1].f[0] * gn[2] * r1), f1 = sigm(vz[1].f[1] * gn[3] * r1);
      const float g0 = tanh_f(vz[2].f[0] * gn[4] * r2), g1 = tanh_f(vz[2].f[1] * gn[5] * r2);
      const float o0 = sigm(vz[3].f[0] * gn[6] * r3), o1 = sigm(vz[3].f[1] * gn[7] * r3);
      c0 = f0 * c0 + i0 * g0;
      c1 = f1 * c1 + i1 * g1;
      float cs = c0 * c0 + c1 * c1;
#pragma unroll
      for (int off = 32; off; off >>= 1) cs += __shfl_xor(cs, off);
      if (lane == 0) p2red[32 + wave] = cs;
      __syncthreads();
      float ct = 0.f;
#pragma unroll
      for (int w = 0; w < 8; ++w) ct += p2red[32 + w];
      const float rc = rsqrtf(ct * inv + 1e-6f);
      const float hx = o0 * tanh_f(c0 * cw0 * rc);
      const float hy = o1 * tanh_f(c1 * cw1 * rc);
      u16* hw;
      if (l2 == 0) hw = h0hist + (size_t)(r + 1) * BH + (size_t)prow * NH + ej;
      else         hw = h1buf + (size_t)(r + 1) * h1step + (size_t)prow * NH + ej;
      const u32 packed = (u32)f2bf(hx) | ((u32)f2bf(hy) << 16);
      __hip_atomic_store(reinterpret_cast<u32*>(hw), packed, AS_RELAXED, SCOPE_AGENT);
      if (l2 == 1 && r == NT) {
        feat[(size_t)prow * NH + ej] = hx;
        feat[(size_t)prow * NH + ej + 1] = hy;
      }
    }
    gridbar(barD, myleaf, ++gen);   // bar2: full barrier (h ready, z consumed)
  }
}

__global__ void __launch_bounds__(256)
head_kernel(const float* __restrict__ feat, const float* __restrict__ Wout,
            const float* __restrict__ bout, const float* __restrict__ stdp,
            float* __restrict__ out) {
  int b = blockIdx.x;
  int a = threadIdx.x >> 5;
  int l = threadIdx.x & 31;
  float s = 0.f;
  for (int k = l; k < NH; k += 32) s += feat[b * NH + k] * Wout[a * NH + k];
#pragma unroll
  for (int off = 16; off; off >>= 1) s += __shfl_xor(s, off, 32);
  if (l == 0) out[b * 8 + a] = s + bout[a];
  if (b == 0 && threadIdx.x < 8) {
    float x = stdp[threadIdx.x];
    float splus = (x > 20.f) ? x : log1pf(__expf(x));
    out[512 + threadIdx.x] = splus + 0.01f;
  }
}

extern "C" void kernel_launch(void* const* d_in, const int* in_sizes, int n_in,
                              void* d_out, int out_size, void* d_ws, size_t ws_size,
                              hipStream_t stream) {
  (void)in_sizes; (void)n_in; (void)out_size;
  const float* obs  = (const float*)d_in[0];
  const float* Wih0 = (const float*)d_in[1];
  const float* Whh0 = (const float*)d_in[2];
  const float* b0   = (const float*)d_in[3];
  const float* gn0  = (const float*)d_in[4];
  const float* cn0  = (const float*)d_in[5];
  const float* Wih1 = (const float*)d_in[6];
  const float* Whh1 = (const float*)d_in[7];
  const float* b1   = (const float*)d_in[8];
  const float* gn1  = (const float*)d_in[9];
  const float* cn1  = (const float*)d_in[10];
  const float* Wout = (const float*)d_in[11];
  const float* bout = (const float*)d_in[12];
  const float* stdp = (const float*)d_in[13];
  float* out = (float*)d_out;

  char* ws = (char*)d_ws;
  size_t off = 0;
  auto take = [&](size_t bytes) -> char* {
    char* p = ws + off;
    off = (off + bytes + 255) & ~(size_t)255;
    return p;
  };

  const size_t WP0_B  = (size_t)128 * 2 * 4 * KT0 * 64 * 16;   // 10.49 MB
  const size_t WP1_B  = (size_t)128 * 2 * 4 * KT1 * 64 * 16;   // 16.78 MB
  const size_t OBST_B = (size_t)NT * NB * NOB * 2;             // 16.78 MB
  const size_t H0H_B  = (size_t)(NT + 1) * BH * 2;             // 67.24 MB
  const size_t H1H_B  = (size_t)(NT + 2) * BH * 2;             // 67.37 MB

  u16* wp0    = (u16*)take(WP0_B);
  u16* wp1    = (u16*)take(WP1_B);
  u16* obsT   = (u16*)take(OBST_B);
  u16* h0hist = (u16*)take(H0H_B);
  u16* h1b    = (u16*)take(H1H_B);              // full history (preferred)
  float* zbuf = (float*)take((size_t)2 * NB * G4H * 4);
  float* feat = (float*)take((size_t)NB * NH * 4);
  int* bars   = (int*)take(8192);               // 2 domains x 512 ints
  bool fits = (off <= ws_size);
  long long h1step = BH;

  if (!fits) {
    // Fallback: single-slot h1 (coherent staging loads).
    off = 0;
    wp0    = (u16*)take(WP0_B);
    wp1    = (u16*)take(WP1_B);
    obsT   = (u16*)take(OBST_B);
    h0hist = (u16*)take(H0H_B);
    h1b    = (u16*)take((size_t)BH * 2);
    zbuf   = (float*)take((size_t)2 * NB * G4H * 4);
    feat   = (float*)take((size_t)NB * NH * 4);
    bars   = (int*)take(8192);
    h1step = 0;
    if (off > ws_size) return;
  }

  (void)hipFuncSetAttribute((const void*)fused_lstm<false>,
                            hipFuncAttributeMaxDynamicSharedMemorySize, LDS_TOTAL);
  (void)hipFuncSetAttribute((const void*)fused_lstm<true>,
                            hipFuncAttributeMaxDynamicSharedMemorySize, LDS_TOTAL);

  (void)hipMemsetAsync(bars, 0, 8192, stream);
  (void)hipMemsetAsync(h0hist, 0, (size_t)BH * 2, stream);               // h0(-1)=0
  (void)hipMemsetAsync(h1b, 0, (size_t)(fits ? 2 : 1) * BH * 2, stream); // h1(-2,-1)=0

  pack_weights<0><<<2560, 256, 0, stream>>>(Wih0, Whh0, wp0);
  pack_weights<1><<<4096, 256, 0, stream>>>(Wih1, Whh1, wp1);
  transpose_obs<<<(NT * NB * NOB) / 256, 256, 0, stream>>>(obs, obsT);

  if (fits) {
    fused_lstm<false><<<NWG, 512, LDS_TOTAL, stream>>>(
        obsT, wp0, wp1, b0, gn0, cn0, b1, gn1, cn1,
        h0hist, h1b, h1step, zbuf, feat, bars);
  } else {
    fused_lstm<true><<<NWG, 512, LDS_TOTAL, stream>>>(
        obsT, wp0, wp1, b0, gn0, cn0, b1, gn1, cn1,
        h0hist, h1b, 0LL, zbuf, feat, bars);
  }

  head_kernel<<<NB, 256, 0, stream>>>(feat, Wout, bout, stdp, out);
}

// Round 16
// 5179.010 us; speedup vs baseline: 1.1369x; 1.1369x over previous
//
#include <hip/hip_runtime.h>
#include <hip/hip_bf16.h>

typedef __attribute__((ext_vector_type(8))) __bf16 bf16x8;
typedef __attribute__((ext_vector_type(4))) float f32x4;
typedef unsigned short u16;
typedef unsigned int u32;
typedef unsigned long long u64;

#define NB 64      // batch
#define NT 512     // timesteps
#define NH 1024    // hidden
#define NOB 256    // obs dim
#define NWG 256    // persistent workgroups (2 independent 128-WG domains)
#define HALF_WG 128
#define G4H 4096   // 4*NH
#define BH (NB*NH) // h-slot elements

// LDS segment layout (per-WG): X = [obs 32x256 | h0 32x1024 | h1 32x1024] bf16
#define S_OBS 0
#define S_H0  16384
#define S_H1  81920
#define LDS_TOTAL 147456

#define KT0 10   // k-tiles per wave, layer 0 (K=1280 / 4 kq / 32)
#define KT1 16   // k-tiles per wave, layer 1 (K=2048 / 4 kq / 32)

#define AS_RELAXED __ATOMIC_RELAXED
#define SCOPE_AGENT __HIP_MEMORY_SCOPE_AGENT
#define KEEPW(x) asm volatile("" : "+v"(x))

// raw sync primitives; sched_barrier(0) pins ordering (guide rule #18)
#define SBAR  do { asm volatile("s_barrier" ::: "memory"); __builtin_amdgcn_sched_barrier(0); } while (0)
#define LGKM0 do { asm volatile("s_waitcnt lgkmcnt(0)" ::: "memory"); __builtin_amdgcn_sched_barrier(0); } while (0)
#define VMW0  do { asm volatile("s_waitcnt vmcnt(0)" ::: "memory"); __builtin_amdgcn_sched_barrier(0); } while (0)
#define VMW8  do { asm volatile("s_waitcnt vmcnt(8)" ::: "memory"); __builtin_amdgcn_sched_barrier(0); } while (0)

__device__ __forceinline__ u16 f2bf(float f) {
  __hip_bfloat16 h = __float2bfloat16(f);
  return *reinterpret_cast<u16*>(&h);
}
__device__ __forceinline__ float sigm(float x) { return 1.f / (1.f + __expf(-x)); }
__device__ __forceinline__ float tanh_f(float x) {
  float e = __expf(2.f * x);
  return 1.f - 2.f / (e + 1.f);
}

// async global->LDS DMA, 16B/lane. LDS dest = wave-uniform base + lane*16;
// global src is per-lane (carries the XOR swizzle). Tracked by vmcnt.
__device__ __forceinline__ void gload_lds16(const void* g, void* l) {
  __builtin_amdgcn_global_load_lds(
      (const __attribute__((address_space(1))) void*)g,
      (__attribute__((address_space(3))) void*)l, 16, 0, 0);
}

// LLC-coherent 16B load (single-slot h1 fallback path only).
__device__ __forceinline__ int4 load_b128_coh(const void* p) {
  int4 v;
  asm volatile("global_load_dwordx4 %0, %1, off sc0 sc1\n\ts_waitcnt vmcnt(0)"
               : "=v"(v) : "v"(p) : "memory");
  return v;
}
__device__ __forceinline__ u64 AL64(const u64* p) {
  return __hip_atomic_load(p, AS_RELAXED, SCOPE_AGENT);
}

// r7-proven flat-poll fence-free barrier, per 128-WG DOMAIN (r14):
// the two bg-domains are fully independent (each computes z/h/obs only for
// its own 32 batch rows after the phase-2 remap), so each domain runs its
// own 16-leaf barrier — halves arrival fan-in and decouples cross-domain
// skew. Arrival after __syncthreads (vmcnt(0) drained -> sc1 data at LLC).
__device__ __forceinline__ void gridbar(int* barD, int myleaf, int gen) {
  __syncthreads();
  if (threadIdx.x < 64) {
    const int lane = threadIdx.x;
    if (lane == 0)
      __hip_atomic_fetch_add(&barD[myleaf * 32], 1, AS_RELAXED, SCOPE_AGENT);
    const int tgt = HALF_WG * gen;
    for (;;) {
      int v = (lane < 16)
            ? __hip_atomic_load(&barD[lane * 32], AS_RELAXED, SCOPE_AGENT) : 0;
#pragma unroll
      for (int off = 8; off; off >>= 1) v += __shfl_xor(v, off);
      v = __shfl(v, 0);
      if (v >= tgt) break;
      __builtin_amdgcn_s_sleep(1);
    }
  }
  __syncthreads();
}

// Per-wave k-tile -> absolute k in X-space (r3-proven mapping).
__device__ __host__ __forceinline__ int wavek0(int kq, int kt) {
  return kt < 2 ? kq * 64 + kt * 32 : 256 + kq * 256 + (kt - 2) * 32;
}
__device__ __host__ __forceinline__ int wavek1(int kq, int kt) {
  return kq * 512 + kt * 32;
}

// Pack fp32 [Wih|Whh] into bf16 MFMA B-fragments (r3-proven layout):
// frag idx = (((slice*2+nt)*4+kq)*KT + kt)*64 + lane
// element: outr = slice*32+nt*16+(lane&15); k = wavek(kq,kt)+(lane>>4)*8+j
template<int LAYER>
__global__ void __launch_bounds__(256)
pack_weights(const float* __restrict__ Wih, const float* __restrict__ Whh,
             u16* __restrict__ wp) {
  constexpr int KT = LAYER ? KT1 : KT0;
  constexpr int KIN = LAYER ? 1024 : 256;
  const int total = 128 * 2 * 4 * KT * 64;
  for (int idx = blockIdx.x * blockDim.x + threadIdx.x; idx < total;
       idx += gridDim.x * blockDim.x) {
    int lane = idx & 63;
    int q = idx >> 6;
    int kt = q % KT; q /= KT;
    int kq = q & 3; q >>= 2;
    int nt = q & 1; q >>= 1;
    int slice = q;
    int outr = slice * 32 + nt * 16 + (lane & 15);
    int kb = (LAYER ? wavek1(kq, kt) : wavek0(kq, kt)) + (lane >> 4) * 8;
    union { u16 uu[8]; int4 qv; } vv;
#pragma unroll
    for (int j = 0; j < 8; ++j) {
      int k = kb + j;
      float f = (k < KIN) ? Wih[(long)outr * KIN + k] : Whh[(long)outr * NH + (k - KIN)];
      vv.uu[j] = f2bf(f);
    }
    reinterpret_cast<int4*>(wp)[idx] = vv.qv;
  }
}

// obsT[t][b][k] = bf16(obs[b][t][k])
__global__ void __launch_bounds__(256)
transpose_obs(const float* __restrict__ obs, u16* __restrict__ obsT) {
  long idx = (long)blockIdx.x * blockDim.x + threadIdx.x;
  if (idx >= (long)NT * NB * NOB) return;
  int k = (int)(idx & (NOB - 1));
  long r = idx >> 8;
  int b = (int)(r & (NB - 1));
  int t = (int)(r >> 6);
  obsT[idx] = f2bf(obs[((long)b * NT + t) * NOB + k]);
}

// Fused two-layer persistent kernel (r7 structure + r14 split barrier domains).
// Round r: L0 step r (r<NT), L1 step r-1 (r>=1). WG = bg (32 batch rows) x
// slice (32 outs). Waves: nt=wave&1 (out half), kq=wave>>1 (K quarter).
// LDS X staged by DMA with pre-swizzled global source; h1 DMA overlaps L0 MFMA
// across a raw barrier (vmcnt(8) -> h0 ready; vmcnt(0) -> h1 ready).
// LDS aliases (r3-proven): partials on S_H1, phase-2 scratch on S_H0.
// Phase 2 (r14 remap, domain-local): WGs with slice<64 in EACH domain own
// (layer = slice>>5, row = bg*32 + (slice&31)) — all data deps stay inside
// the domain, so the two 128-WG domains never synchronize with each other.
template<bool H1COH>
__global__ void __launch_bounds__(512)
fused_lstm(const u16* __restrict__ obsT,
           const u16* __restrict__ wp0, const u16* __restrict__ wp1,
           const float* __restrict__ b0, const float* __restrict__ gn0,
           const float* __restrict__ cn0,
           const float* __restrict__ b1, const float* __restrict__ gn1,
           const float* __restrict__ cn1,
           u16* __restrict__ h0hist, u16* __restrict__ h1buf, long long h1step,
           float* __restrict__ zbuf, float* __restrict__ feat,
           int* __restrict__ bar) {
  extern __shared__ char smem[];
  f32x4* sred = reinterpret_cast<f32x4*>(smem + S_H1);   // aliases h1-seg (dead)
  float* p2red = reinterpret_cast<float*>(smem + S_H0);  // aliases h0-seg (dead)

  const int tid = threadIdx.x;
  const int lane = tid & 63;
  const int wave = tid >> 6;
  const int nt = wave & 1;
  const int kq = wave >> 1;
  const int col = lane & 15;
  const int rgrp = lane >> 4;
  const int wg = blockIdx.x;
  const int bg = wg >> 7;
  const int slice = wg & 127;
  const int kl = (wave & 1) * 64 + lane;  // h-seg chunk-in-row for DMA
  const int w2 = wave >> 1;               // h-seg row group for DMA
  int* barD = bar + bg * 512;             // own domain's 16-leaf region
  const int myleaf = slice & 15;

  // ---- persistent weight fragments (both layers) ----
  bf16x8 wf0[KT0], wf1[KT1];
  {
    const bf16x8* p0 = reinterpret_cast<const bf16x8*>(wp0)
                     + ((size_t)((slice * 2 + nt) * 4 + kq) * KT0) * 64 + lane;
#pragma unroll
    for (int u = 0; u < KT0; ++u) { wf0[u] = p0[u * 64]; KEEPW(wf0[u]); }
    const bf16x8* p1 = reinterpret_cast<const bf16x8*>(wp1)
                     + ((size_t)((slice * 2 + nt) * 4 + kq) * KT1) * 64 + lane;
#pragma unroll
    for (int u = 0; u < KT1; ++u) { wf1[u] = p1[u * 64]; KEEPW(wf1[u]); }
  }

  // ---- phase-2 constants/state (slice<64 in each domain, r14 remap) ----
  const bool p2wg = (slice < 64);
  const int l2 = (slice >> 5) & 1;            // 0: layer0, 1: layer1
  const int prow = bg * 32 + (slice & 31);    // own-domain batch row
  const int ej = tid * 2;
  float gn[8];
  float cw0 = 0.f, cw1 = 0.f;
  float c0 = 0.f, c1 = 0.f;
  if (p2wg) {
    const float* gnp = l2 ? gn1 : gn0;
    const float* cnp = l2 ? cn1 : cn0;
#pragma unroll
    for (int g = 0; g < 4; ++g) {
      gn[g * 2]     = gnp[g * NH + ej];
      gn[g * 2 + 1] = gnp[g * NH + ej + 1];
    }
    cw0 = cnp[ej];
    cw1 = cnp[ej + 1];
  }
  constexpr float inv = 1.f / 1024.f;

  // ---- prologue: issue obs(0) DMA (drained by round 0's VMW8, in-order) ----
  {
    const u16* os = obsT + (size_t)(bg * 32) * NOB;
#pragma unroll
    for (int i = 0; i < 2; ++i) {
      const int row = 16 * i + 2 * wave + (lane >> 5);
      gload_lds16(os + (size_t)row * NOB + (size_t)(((lane & 31) ^ (row & 7)) * 8),
                  smem + S_OBS + (i * 512 + wave * 64) * 16);
    }
  }

  int gen = 0;

  for (int r = 0; r <= NT; ++r) {
    // -------- issue h0 / h1 staging DMA (slot r) --------
    const u16* h0s = h0hist + (size_t)r * BH + (size_t)(bg * 32) * NH;
    const u16* h1s = h1buf + (size_t)r * h1step + (size_t)(bg * 32) * NH;
#pragma unroll
    for (int i = 0; i < 8; ++i) {
      const int row = i * 4 + w2;
      const int koff = (kl ^ (row & 7)) * 8;
      gload_lds16(h0s + (size_t)row * NH + koff,
                  smem + S_H0 + (i * 512 + wave * 64) * 16);
    }
    if constexpr (!H1COH) {
#pragma unroll
      for (int i = 0; i < 8; ++i) {
        const int row = i * 4 + w2;
        const int koff = (kl ^ (row & 7)) * 8;
        gload_lds16(h1s + (size_t)row * NH + koff,
                    smem + S_H1 + (i * 512 + wave * 64) * 16);
      }
      VMW8;   // obs leftovers + own h0 landed (h1's 8 still in flight)
      SBAR;   // all waves' h0 in LDS; h1 DMA flies across the barrier
    } else {
      // fallback: manual coherent h1 staging (single-slot buffer)
#pragma unroll 1
      for (int c = tid; c < 4096; c += 512) {
        int row = c >> 7, kc = c & 127;
        int4 v = load_b128_coh(h1s + (size_t)row * NH + kc * 8);
        *reinterpret_cast<int4*>(smem + S_H1 + row * 2048 + ((kc ^ (row & 7)) << 4)) = v;
      }
      VMW0; LGKM0;
      SBAR;   // obs + h0 + h1 all in LDS
    }

    // -------- L0 GEMM (reads S_OBS + S_H0 only) --------
    f32x4 a00 = {0,0,0,0}, a01 = {0,0,0,0};
    f32x4 a10 = {0,0,0,0}, a11 = {0,0,0,0};
    if (r < NT) {
#pragma unroll
      for (int kt = 0; kt < KT0; ++kt) {
        const int base   = (kt < 2) ? S_OBS : S_H0;
        const int rowstr = (kt < 2) ? 512 : 2048;
        const int chunk0 = (kt < 2) ? (kq * 8 + kt * 4) : (kq * 32 + (kt - 2) * 4);
        const int sw = (((chunk0 + rgrp) ^ (col & 7)) << 4);
        bf16x8 am0 = *reinterpret_cast<const bf16x8*>(smem + base + col * rowstr + sw);
        bf16x8 am1 = *reinterpret_cast<const bf16x8*>(smem + base + (16 + col) * rowstr + sw);
        a00 = __builtin_amdgcn_mfma_f32_16x16x32_bf16(am0, wf0[kt], a00, 0, 0, 0);
        a01 = __builtin_amdgcn_mfma_f32_16x16x32_bf16(am1, wf0[kt], a01, 0, 0, 0);
      }
    }
    if constexpr (!H1COH) {
      VMW0;   // own h1 DMA landed
      SBAR;   // everyone's h1 landed
    }

    // -------- L1 GEMM (reads S_H0 + S_H1) --------
    if (r >= 1) {
      const int base = (kq < 2) ? S_H0 : S_H1;
#pragma unroll
      for (int kt = 0; kt < KT1; ++kt) {
        const int chunk0 = (kq & 1) * 64 + kt * 4;
        const int sw = (((chunk0 + rgrp) ^ (col & 7)) << 4);
        bf16x8 am0 = *reinterpret_cast<const bf16x8*>(smem + base + col * 2048 + sw);
        bf16x8 am1 = *reinterpret_cast<const bf16x8*>(smem + base + (16 + col) * 2048 + sw);
        a10 = __builtin_amdgcn_mfma_f32_16x16x32_bf16(am0, wf1[kt], a10, 0, 0, 0);
        a11 = __builtin_amdgcn_mfma_f32_16x16x32_bf16(am1, wf1[kt], a11, 0, 0, 0);
      }
    }
    LGKM0;
    SBAR;   // all LDS X reads done (obs/h0/h1 segments now dead)

    // -------- cross-wave K-reduction in LDS; z -> LLC (sc1) --------
    // writer: wave w = 2*kq + nt stores its 4 accumulators at
    // sred[w*512 + lm*64 + lane], lm = l*2 + m.
    {
      f32x4* pw = sred + wave * 512 + lane;
      pw[0 * 64] = a00;  // l=0,m=0
      pw[1 * 64] = a01;  // l=0,m=1
      pw[2 * 64] = a10;  // l=1,m=0
      pw[3 * 64] = a11;  // l=1,m=1
    }
    LGKM0;
    SBAR;
    {
      // reducer wave q handles (lm = q&3, out-half nq2 = q>>2): sums the four
      // K-quarter partials of out-half nq2 = waves {nq2, nq2+2, nq2+4, nq2+6}.
      const int q = tid >> 6, ln = tid & 63;
      const int fcol = ln & 15, frg = ln >> 4;
      const int lm = q & 3;      // l*2+m
      const int nq2 = q >> 2;    // out-half to reduce
      f32x4 s = sred[(nq2 + 0) * 512 + lm * 64 + ln]
              + sred[(nq2 + 2) * 512 + lm * 64 + ln]
              + sred[(nq2 + 4) * 512 + lm * 64 + ln]
              + sred[(nq2 + 6) * 512 + lm * 64 + ln];
      const int l = lm >> 1, m = lm & 1;
      const bool zv = l ? (r >= 1) : (r < NT);
      if (zv) {
        const int outg = slice * 32 + nq2 * 16 + fcol;
        const float bv = (l ? b1 : b0)[outg];
        float* zr = zbuf + ((size_t)l * NB + bg * 32 + m * 16 + frg * 4) * G4H + outg;
#pragma unroll
        for (int j = 0; j < 4; ++j)
          __hip_atomic_store(&zr[(size_t)j * G4H], s[j] + bv, AS_RELAXED, SCOPE_AGENT);
      }
    }
    gridbar(barD, myleaf, ++gen);

    // -------- obs(r+1) prefetch DMA (drains during phase-2 / bar2) --------
    if (r + 1 < NT) {
      const u16* os = obsT + (size_t)(r + 1) * (NB * NOB) + (size_t)(bg * 32) * NOB;
#pragma unroll
      for (int i = 0; i < 2; ++i) {
        const int row = 16 * i + 2 * wave + (lane >> 5);
        gload_lds16(os + (size_t)row * NOB + (size_t)(((lane & 31) ^ (row & 7)) * 8),
                    smem + S_OBS + (i * 512 + wave * 64) * 16);
      }
    }

    // -------- phase 2: slice<64 in each domain, own (layer,row) --------
    if (p2wg && (l2 ? (r >= 1) : (r < NT))) {
      const u64* zq = reinterpret_cast<const u64*>(
          zbuf + ((size_t)l2 * NB + prow) * G4H);
      union { u64 q; float f[2]; } va, vb, vg, vo;
      va.q = AL64(zq + tid);
      vb.q = AL64(zq + 512 + tid);
      vg.q = AL64(zq + 1024 + tid);
      vo.q = AL64(zq + 1536 + tid);
      float s0 = va.f[0] * va.f[0] + va.f[1] * va.f[1];
      float s1 = vb.f[0] * vb.f[0] + vb.f[1] * vb.f[1];
      float s2 = vg.f[0] * vg.f[0] + vg.f[1] * vg.f[1];
      float s3 = vo.f[0] * vo.f[0] + vo.f[1] * vo.f[1];
#pragma unroll
      for (int off = 32; off; off >>= 1) {
        s0 += __shfl_xor(s0, off);
        s1 += __shfl_xor(s1, off);
        s2 += __shfl_xor(s2, off);
        s3 += __shfl_xor(s3, off);
      }
      if (lane == 0) {
        float* sp = p2red + wave * 4;
        sp[0] = s0; sp[1] = s1; sp[2] = s2; sp[3] = s3;
      }
      __syncthreads();
      float t0 = 0.f, t1 = 0.f, t2 = 0.f, t3 = 0.f;
#pragma unroll
      for (int w = 0; w < 8; ++w) {
        t0 += p2red[w * 4 + 0]; t1 += p2red[w * 4 + 1];
        t2 += p2red[w * 4 + 2]; t3 += p2red[w * 4 + 3];
      }
      const float r0 = rsqrtf(t0 * inv + 1e-6f);
      const float r1 = rsqrtf(t1 * inv + 1e-6f);
      const float r2 = rsqrtf(t2 * inv + 1e-6f);
      const float r3 = rsqrtf(t3 * inv + 1e-6f);
      const float i0 = sigm(va.f[0] * gn[0] * r0), i1 = sigm(va.f[1] * gn[1] * r0);
      const float f0 = sigm(vb.f[0] * gn[2] * r1), f1 = sigm(vb.f[1] * gn[3] * r1);
      const float g0 = tanh_f(vg.f[0] * gn[4] * r2), g1 = tanh_f(vg.f[1] * gn[5] * r2);
      const float o0 = sigm(vo.f[0] * gn[6] * r3), o1 = sigm(vo.f[1] * gn[7] * r3);
      c0 = f0 * c0 + i0 * g0;
      c1 = f1 * c1 + i1 * g1;
      float cs = c0 * c0 + c1 * c1;
#pragma unroll
      for (int off = 32; off; off >>= 1) cs += __shfl_xor(cs, off);
      if (lane == 0) p2red[32 + wave] = cs;
      __syncthreads();
      float ct = 0.f;
#pragma unroll
      for (int w = 0; w < 8; ++w) ct += p2red[32 + w];
      const float rc = rsqrtf(ct * inv + 1e-6f);
      const float hx = o0 * tanh_f(c0 * cw0 * rc);
      const float hy = o1 * tanh_f(c1 * cw1 * rc);
      u16* hw;
      if (l2 == 0) hw = h0hist + (size_t)(r + 1) * BH + (size_t)prow * NH + ej;
      else         hw = h1buf + (size_t)(r + 1) * h1step + (size_t)prow * NH + ej;
      const u32 packed = (u32)f2bf(hx) | ((u32)f2bf(hy) << 16);
      __hip_atomic_store(reinterpret_cast<u32*>(hw), packed, AS_RELAXED, SCOPE_AGENT);
      if (l2 == 1 && r == NT) {
        feat[(size_t)prow * NH + ej] = hx;
        feat[(size_t)prow * NH + ej + 1] = hy;
      }
    }
    gridbar(barD, myleaf, ++gen);
  }
}

__global__ void __launch_bounds__(256)
head_kernel(const float* __restrict__ feat, const float* __restrict__ Wout,
            const float* __restrict__ bout, const float* __restrict__ stdp,
            float* __restrict__ out) {
  int b = blockIdx.x;
  int a = threadIdx.x >> 5;
  int l = threadIdx.x & 31;
  float s = 0.f;
  for (int k = l; k < NH; k += 32) s += feat[b * NH + k] * Wout[a * NH + k];
#pragma unroll
  for (int off = 16; off; off >>= 1) s += __shfl_xor(s, off, 32);
  if (l == 0) out[b * 8 + a] = s + bout[a];
  if (b == 0 && threadIdx.x < 8) {
    float x = stdp[threadIdx.x];
    float splus = (x > 20.f) ? x : log1pf(__expf(x));
    out[512 + threadIdx.x] = splus + 0.01f;
  }
}

extern "C" void kernel_launch(void* const* d_in, const int* in_sizes, int n_in,
                              void* d_out, int out_size, void* d_ws, size_t ws_size,
                              hipStream_t stream) {
  (void)in_sizes; (void)n_in; (void)out_size;
  const float* obs  = (const float*)d_in[0];
  const float* Wih0 = (const float*)d_in[1];
  const float* Whh0 = (const float*)d_in[2];
  const float* b0   = (const float*)d_in[3];
  const float* gn0  = (const float*)d_in[4];
  const float* cn0  = (const float*)d_in[5];
  const float* Wih1 = (const float*)d_in[6];
  const float* Whh1 = (const float*)d_in[7];
  const float* b1   = (const float*)d_in[8];
  const float* gn1  = (const float*)d_in[9];
  const float* cn1  = (const float*)d_in[10];
  const float* Wout = (const float*)d_in[11];
  const float* bout = (const float*)d_in[12];
  const float* stdp = (const float*)d_in[13];
  float* out = (float*)d_out;

  char* ws = (char*)d_ws;
  size_t off = 0;
  auto take = [&](size_t bytes) -> char* {
    char* p = ws + off;
    off = (off + bytes + 255) & ~(size_t)255;
    return p;
  };

  const size_t WP0_B  = (size_t)128 * 2 * 4 * KT0 * 64 * 16;   // 10.49 MB
  const size_t WP1_B  = (size_t)128 * 2 * 4 * KT1 * 64 * 16;   // 16.78 MB
  const size_t OBST_B = (size_t)NT * NB * NOB * 2;             // 16.78 MB
  const size_t H0H_B  = (size_t)(NT + 1) * BH * 2;             // 67.24 MB
  const size_t H1H_B  = (size_t)(NT + 2) * BH * 2;             // 67.37 MB

  u16* wp0    = (u16*)take(WP0_B);
  u16* wp1    = (u16*)take(WP1_B);
  u16* obsT   = (u16*)take(OBST_B);
  u16* h0hist = (u16*)take(H0H_B);
  u16* h1b    = (u16*)take(H1H_B);              // full history (preferred)
  float* zbuf = (float*)take((size_t)2 * NB * G4H * 4);
  float* feat = (float*)take((size_t)NB * NH * 4);
  int* bars   = (int*)take(8192);               // 2 domains x 512 ints
  bool fits = (off <= ws_size);
  long long h1step = BH;

  if (!fits) {
    // Fallback: single-slot h1 (coherent staging loads).
    off = 0;
    wp0    = (u16*)take(WP0_B);
    wp1    = (u16*)take(WP1_B);
    obsT   = (u16*)take(OBST_B);
    h0hist = (u16*)take(H0H_B);
    h1b    = (u16*)take((size_t)BH * 2);
    zbuf   = (float*)take((size_t)2 * NB * G4H * 4);
    feat   = (float*)take((size_t)NB * NH * 4);
    bars   = (int*)take(8192);
    h1step = 0;
    if (off > ws_size) return;
  }

  (void)hipFuncSetAttribute((const void*)fused_lstm<false>,
                            hipFuncAttributeMaxDynamicSharedMemorySize, LDS_TOTAL);
  (void)hipFuncSetAttribute((const void*)fused_lstm<true>,
                            hipFuncAttributeMaxDynamicSharedMemorySize, LDS_TOTAL);

  (void)hipMemsetAsync(bars, 0, 8192, stream);
  (void)hipMemsetAsync(h0hist, 0, (size_t)BH * 2, stream);               // h0(-1)=0
  (void)hipMemsetAsync(h1b, 0, (size_t)(fits ? 2 : 1) * BH * 2, stream); // h1(-2,-1)=0

  pack_weights<0><<<2560, 256, 0, stream>>>(Wih0, Whh0, wp0);
  pack_weights<1><<<4096, 256, 0, stream>>>(Wih1, Whh1, wp1);
  transpose_obs<<<(NT * NB * NOB) / 256, 256, 0, stream>>>(obs, obsT);

  if (fits) {
    fused_lstm<false><<<NWG, 512, LDS_TOTAL, stream>>>(
        obsT, wp0, wp1, b0, gn0, cn0, b1, gn1, cn1,
        h0hist, h1b, h1step, zbuf, feat, bars);
  } else {
    fused_lstm<true><<<NWG, 512, LDS_TOTAL, stream>>>(
        obsT, wp0, wp1, b0, gn0, cn0, b1, gn1, cn1,
        h0hist, h1b, 0LL, zbuf, feat, bars);
  }

  head_kernel<<<NB, 256, 0, stream>>>(feat, Wout, bout, stdp, out);
}